// Round 1
// baseline (1107.394 us; speedup 1.0000x reference)
//
#include <hip/hip_runtime.h>

// MoE-LoRA linear, MI355X (gfx950).
// out = x @ base_w^T + 2.0 * ((x @ lora_A^T) * topk_gate_w) @ lora_B^T
// Strategy: bf16 MFMA GEMM with K-concatenation:
//   A_cat[8192][4608] = [ bf16(x) | bf16(SCALING * w_e * (x . lora_A_row)) ]
//   W_cat[4096][4608] = [ bf16(base_w) | bf16(lora_B) ]
//   out = A_cat @ W_cat^T   (single 128x128-tile MFMA GEMM, K=4608)

#define D_IN   4096
#define D_OUT  4096
#define NTOK   8192      // B*S
#define NE     32
#define RK     16
#define RMOE   512       // NE*RK
#define KCAT   4608      // D_IN + RMOE
#define SCALING 2.0f

typedef unsigned short u16;
typedef __attribute__((ext_vector_type(4))) float  f32x4;
typedef __attribute__((ext_vector_type(4))) unsigned short u16x4;
typedef __attribute__((ext_vector_type(8))) short  bf16x8;

__device__ __forceinline__ u16 f2bf(float f) {
  unsigned u = __float_as_uint(f);
  u += 0x7FFFu + ((u >> 16) & 1u);        // round-to-nearest-even
  return (u16)(u >> 16);
}

__device__ __forceinline__ void gload16(const void* g, void* l) {
  __builtin_amdgcn_global_load_lds(
      (const __attribute__((address_space(1))) unsigned*)g,
      (__attribute__((address_space(3))) unsigned*)l, 16, 0, 0);
}

// ---------------------------------------------------------------------------
// Kernel 1: per-token gating + x -> bf16 conversion into A_cat[:, 0:4096]
// ---------------------------------------------------------------------------
__global__ __launch_bounds__(256) void k_gate(
    const float* __restrict__ x, const float* __restrict__ gate_w,
    u16* __restrict__ xb, float* __restrict__ wdense)
{
  __shared__ float xs[D_IN];
  __shared__ float lg[NE];
  const int token = blockIdx.x;
  const int tid = threadIdx.x;
  const int lane = tid & 63, wave = tid >> 6;
  const float* xrow = x + (size_t)token * D_IN;
  u16* xbrow = xb + (size_t)token * KCAT;

  // stage x row to LDS (fp32) + write bf16 copy to A_cat
#pragma unroll
  for (int i = 0; i < 4; ++i) {
    int c = tid + i * 256;                    // 1024 chunks of 4 floats
    f32x4 v = ((const f32x4*)xrow)[c];
    xs[c * 4 + 0] = v[0]; xs[c * 4 + 1] = v[1];
    xs[c * 4 + 2] = v[2]; xs[c * 4 + 3] = v[3];
    u16x4 h;
    h[0] = f2bf(v[0]); h[1] = f2bf(v[1]); h[2] = f2bf(v[2]); h[3] = f2bf(v[3]);
    ((u16x4*)xbrow)[c] = h;
  }
  __syncthreads();

  // logits: wave w handles experts w*8 .. w*8+7 (fp32, matches ref selection)
#pragma unroll
  for (int ei = 0; ei < 8; ++ei) {
    int e = wave * 8 + ei;
    const float* gw = gate_w + (size_t)e * D_IN;
    float s = 0.f;
    for (int j = lane; j < D_IN; j += 64) s += xs[j] * gw[j];
#pragma unroll
    for (int off = 32; off > 0; off >>= 1) s += __shfl_down(s, off);
    if (lane == 0) lg[e] = s;
  }
  __syncthreads();

  // top-2 (redundant per thread; strict > keeps lowest index on ties = jax top_k)
  float l1 = -1e30f; int e1 = 0;
  for (int e = 0; e < NE; ++e) { float v = lg[e]; if (v > l1) { l1 = v; e1 = e; } }
  float l2 = -1e30f; int e2 = 0;
  for (int e = 0; e < NE; ++e) { if (e == e1) continue; float v = lg[e]; if (v > l2) { l2 = v; e2 = e; } }
  // renormalized top-2 softmax == softmax over {l1,l2}
  float t = __expf(l2 - l1);
  float w2 = t / (1.f + t), w1 = 1.f - w2;
  if (tid < NE)
    wdense[(size_t)token * NE + tid] = (tid == e1) ? w1 : (tid == e2) ? w2 : 0.f;
}

// ---------------------------------------------------------------------------
// Kernel 2: weight conversion to bf16 (W_cat = [base_w | lora_B], la = lora_A)
// ---------------------------------------------------------------------------
__global__ __launch_bounds__(256) void k_wconv(
    const float* __restrict__ base_w, const float* __restrict__ lora_B,
    const float* __restrict__ lora_A, u16* __restrict__ wb, u16* __restrict__ la)
{
  const int bid = blockIdx.x, tid = threadIdx.x;
  if (bid < D_OUT) {
    const float* src = base_w + (size_t)bid * D_IN;
    u16* dst = wb + (size_t)bid * KCAT;
#pragma unroll
    for (int i = 0; i < 4; ++i) {
      int c = tid + i * 256;
      f32x4 v = ((const f32x4*)src)[c];
      u16x4 h; h[0] = f2bf(v[0]); h[1] = f2bf(v[1]); h[2] = f2bf(v[2]); h[3] = f2bf(v[3]);
      ((u16x4*)dst)[c] = h;
    }
    if (tid < 128) {                          // lora_B row: 512 = 128 x float4
      f32x4 v = ((const f32x4*)(lora_B + (size_t)bid * RMOE))[tid];
      u16x4 h; h[0] = f2bf(v[0]); h[1] = f2bf(v[1]); h[2] = f2bf(v[2]); h[3] = f2bf(v[3]);
      ((u16x4*)(dst + D_IN))[tid] = h;
    }
  } else {
    int r = bid - D_OUT;                      // lora_A row 0..511
    const float* src = lora_A + (size_t)r * D_IN;
    u16* dst = la + (size_t)r * D_IN;
#pragma unroll
    for (int i = 0; i < 4; ++i) {
      int c = tid + i * 256;
      f32x4 v = ((const f32x4*)src)[c];
      u16x4 h; h[0] = f2bf(v[0]); h[1] = f2bf(v[1]); h[2] = f2bf(v[2]); h[3] = f2bf(v[3]);
      ((u16x4*)dst)[c] = h;
    }
  }
}

// ---------------------------------------------------------------------------
// Kernel 3: ax GEMM  (A_cat[:, :4096] @ lora_A^T) * w * SCALING -> A_cat tail
// m97 structure: 128x128 tile, BK=64, 4 waves (2x2), 16x16x32 bf16 MFMA
// ---------------------------------------------------------------------------
__global__ __launch_bounds__(256) void k_gemm_ax(
    const u16* __restrict__ A, const u16* __restrict__ Bw,
    const float* __restrict__ wdense, u16* __restrict__ xb)
{
  __shared__ u16 As[128 * 64];
  __shared__ u16 Bs[128 * 64];
  const int nbx = RMOE / 128;                 // 4
  const int nwg = gridDim.x;                  // 256 (div by 8 -> bijective swizzle)
  int bid = blockIdx.x;
  int wg = (bid & 7) * (nwg >> 3) + (bid >> 3);
  const int tm = wg / nbx, tn = wg % nbx;
  const int tid = threadIdx.x;
  const int lane = tid & 63, wave = tid >> 6;
  const int wr = wave >> 1, wc = wave & 1;

  f32x4 acc[4][4];
#pragma unroll
  for (int i = 0; i < 4; ++i)
#pragma unroll
    for (int j = 0; j < 4; ++j) acc[i][j] = (f32x4){0.f, 0.f, 0.f, 0.f};

  const int row0 = tm * 128, col0 = tn * 128;
  for (int kt = 0; kt < D_IN / 64; ++kt) {
    __syncthreads();
#pragma unroll
    for (int i = 0; i < 4; ++i) {
      int c = tid + i * 256;
      int r = c >> 3, c8 = c & 7;
      gload16(A  + (size_t)(row0 + r) * KCAT + kt * 64 + c8 * 8, &As[c * 8]);
      gload16(Bw + (size_t)(col0 + r) * D_IN + kt * 64 + c8 * 8, &Bs[c * 8]);
    }
    __syncthreads();
#pragma unroll
    for (int kk = 0; kk < 2; ++kk) {
      bf16x8 af[4], bfr[4];
      int ko = kk * 32 + (lane >> 4) * 8;
#pragma unroll
      for (int i = 0; i < 4; ++i) {
        af[i]  = *(const bf16x8*)&As[(wr * 64 + i * 16 + (lane & 15)) * 64 + ko];
        bfr[i] = *(const bf16x8*)&Bs[(wc * 64 + i * 16 + (lane & 15)) * 64 + ko];
      }
#pragma unroll
      for (int i = 0; i < 4; ++i)
#pragma unroll
        for (int j = 0; j < 4; ++j)
          acc[i][j] = __builtin_amdgcn_mfma_f32_16x16x32_bf16(af[i], bfr[j], acc[i][j], 0, 0, 0);
    }
  }
  // epilogue: scale by gate weight, SCALING, store bf16 to A_cat tail
#pragma unroll
  for (int i = 0; i < 4; ++i) {
    int rbase = row0 + wr * 64 + i * 16 + ((lane >> 4) << 2);
#pragma unroll
    for (int j = 0; j < 4; ++j) {
      int cb = col0 + wc * 64 + j * 16 + (lane & 15);
#pragma unroll
      for (int q = 0; q < 4; ++q) {
        int trow = rbase + q;
        float wgt = wdense[(size_t)trow * NE + (cb >> 4)];
        xb[(size_t)trow * KCAT + D_IN + cb] = f2bf(acc[i][j][q] * wgt * SCALING);
      }
    }
  }
}

// ---------------------------------------------------------------------------
// Kernel 4: main GEMM  out = A_cat @ W_cat^T   (M=8192, N=4096, K=4608)
// ---------------------------------------------------------------------------
__global__ __launch_bounds__(256) void k_gemm_main(
    const u16* __restrict__ A, const u16* __restrict__ Bw, float* __restrict__ C)
{
  __shared__ u16 As[128 * 64];
  __shared__ u16 Bs[128 * 64];
  const int nbx = D_OUT / 128;                // 32
  const int nwg = gridDim.x;                  // 2048 (div by 8)
  int bid = blockIdx.x;
  int wg = (bid & 7) * (nwg >> 3) + (bid >> 3);
  const int tm = wg / nbx, tn = wg % nbx;
  const int tid = threadIdx.x;
  const int lane = tid & 63, wave = tid >> 6;
  const int wr = wave >> 1, wc = wave & 1;

  f32x4 acc[4][4];
#pragma unroll
  for (int i = 0; i < 4; ++i)
#pragma unroll
    for (int j = 0; j < 4; ++j) acc[i][j] = (f32x4){0.f, 0.f, 0.f, 0.f};

  const int row0 = tm * 128, col0 = tn * 128;
  for (int kt = 0; kt < KCAT / 64; ++kt) {    // 72 iters
    __syncthreads();
#pragma unroll
    for (int i = 0; i < 4; ++i) {
      int c = tid + i * 256;
      int r = c >> 3, c8 = c & 7;
      gload16(A  + (size_t)(row0 + r) * KCAT + kt * 64 + c8 * 8, &As[c * 8]);
      gload16(Bw + (size_t)(col0 + r) * KCAT + kt * 64 + c8 * 8, &Bs[c * 8]);
    }
    __syncthreads();
#pragma unroll
    for (int kk = 0; kk < 2; ++kk) {
      bf16x8 af[4], bfr[4];
      int ko = kk * 32 + (lane >> 4) * 8;
#pragma unroll
      for (int i = 0; i < 4; ++i) {
        af[i]  = *(const bf16x8*)&As[(wr * 64 + i * 16 + (lane & 15)) * 64 + ko];
        bfr[i] = *(const bf16x8*)&Bs[(wc * 64 + i * 16 + (lane & 15)) * 64 + ko];
      }
#pragma unroll
      for (int i = 0; i < 4; ++i)
#pragma unroll
        for (int j = 0; j < 4; ++j)
          acc[i][j] = __builtin_amdgcn_mfma_f32_16x16x32_bf16(af[i], bfr[j], acc[i][j], 0, 0, 0);
    }
  }
#pragma unroll
  for (int i = 0; i < 4; ++i) {
    int rbase = row0 + wr * 64 + i * 16 + ((lane >> 4) << 2);
#pragma unroll
    for (int j = 0; j < 4; ++j) {
      int cb = col0 + wc * 64 + j * 16 + (lane & 15);
#pragma unroll
      for (int q = 0; q < 4; ++q)
        C[(size_t)(rbase + q) * D_OUT + cb] = acc[i][j][q];
    }
  }
}

// ---------------------------------------------------------------------------
extern "C" void kernel_launch(void* const* d_in, const int* in_sizes, int n_in,
                              void* d_out, int out_size, void* d_ws, size_t ws_size,
                              hipStream_t stream) {
  const float* x      = (const float*)d_in[0];
  const float* base_w = (const float*)d_in[1];
  const float* gate_w = (const float*)d_in[2];
  const float* lora_A = (const float*)d_in[3];
  const float* lora_B = (const float*)d_in[4];
  float* out = (float*)d_out;

  char* ws = (char*)d_ws;
  u16* xb       = (u16*)ws;                                    // 8192*4608*2 = 75,497,472 B
  u16* wb       = (u16*)(ws + 75497472);                       // 4096*4608*2 = 37,748,736 B
  u16* la       = (u16*)(ws + 75497472 + 37748736);            //  512*4096*2 =  4,194,304 B
  float* wdense = (float*)(ws + 75497472 + 37748736 + 4194304); // 8192*32*4  =  1,048,576 B
  // total ~118.5 MB of workspace

  hipLaunchKernelGGL(k_gate,      dim3(NTOK),        dim3(256), 0, stream, x, gate_w, xb, wdense);
  hipLaunchKernelGGL(k_wconv,     dim3(D_OUT + RMOE),dim3(256), 0, stream, base_w, lora_B, lora_A, wb, la);
  hipLaunchKernelGGL(k_gemm_ax,   dim3((NTOK/128) * (RMOE/128)), dim3(256), 0, stream, xb, la, wdense, xb);
  hipLaunchKernelGGL(k_gemm_main, dim3((NTOK/128) * (D_OUT/128)), dim3(256), 0, stream, xb, wb, out);
}

// Round 2
// 667.815 us; speedup vs baseline: 1.6582x; 1.6582x over previous
//
#include <hip/hip_runtime.h>

// MoE-LoRA linear, MI355X (gfx950).
// out = x @ base_w^T + 2.0 * ((x @ lora_A^T) * topk_gate_w) @ lora_B^T
// Strategy: bf16 MFMA GEMM with K-concatenation:
//   A_cat[8192][4608] = [ bf16(x) | bf16(SCALING * w_e * (x . lora_A_row)) ]
//   W_cat[4096][4608] = [ bf16(base_w) | bf16(lora_B) ]
//   out = A_cat @ W_cat^T
// Gating (fp32-exact top-2) done as a register-blocked fp32 tiled GEMM.

#define D_IN   4096
#define D_OUT  4096
#define NTOK   8192      // B*S
#define NE     32
#define RK     16
#define RMOE   512       // NE*RK
#define KCAT   4608      // D_IN + RMOE
#define SCALING 2.0f

typedef unsigned short u16;
typedef __attribute__((ext_vector_type(4))) float  f32x4;
typedef __attribute__((ext_vector_type(4))) unsigned short u16x4;
typedef __attribute__((ext_vector_type(8))) short  bf16x8;

__device__ __forceinline__ u16 f2bf(float f) {
  unsigned u = __float_as_uint(f);
  u += 0x7FFFu + ((u >> 16) & 1u);        // round-to-nearest-even
  return (u16)(u >> 16);
}

__device__ __forceinline__ void gload16(const void* g, void* l) {
  __builtin_amdgcn_global_load_lds(
      (const __attribute__((address_space(1))) unsigned*)g,
      (__attribute__((address_space(3))) unsigned*)l, 16, 0, 0);
}

// ---------------------------------------------------------------------------
// Kernel 1a: streaming x -> bf16 into A_cat[:, 0:4096]  (pure BW, ~30 us)
// ---------------------------------------------------------------------------
__global__ __launch_bounds__(256) void k_conv_x(
    const float* __restrict__ x, u16* __restrict__ xb)
{
  const int tok = blockIdx.x;
  const int tid = threadIdx.x;
  const f32x4* src = (const f32x4*)(x + (size_t)tok * D_IN);
  u16x4* dst = (u16x4*)(xb + (size_t)tok * KCAT);
#pragma unroll
  for (int i = 0; i < 4; ++i) {
    int c = tid + i * 256;                  // 1024 f32x4 per row
    f32x4 v = src[c];
    u16x4 h;
    h[0] = f2bf(v[0]); h[1] = f2bf(v[1]); h[2] = f2bf(v[2]); h[3] = f2bf(v[3]);
    dst[c] = h;
  }
}

// ---------------------------------------------------------------------------
// Kernel 1b: gating logits (fp32 tiled GEMM) + top-2 + renorm -> wdense
// 256 blocks x 32 tokens; waves split K 4-way; per-thread 4 tok x 4 experts.
// LDS rows padded +4 floats: staged writes and b128 tile reads conflict-free.
// ---------------------------------------------------------------------------
#define TT 32
#define KC 256
#define LPAD (KC + 4)

__global__ __launch_bounds__(256) void k_logits(
    const float* __restrict__ x, const float* __restrict__ gate_w,
    float* __restrict__ wdense)
{
  __shared__ float smem[2 * TT * LPAD];     // xs | gs  (66,560 B)
  __shared__ int   e1s[TT]; __shared__ int   e2s[TT];
  __shared__ float w1s[TT]; __shared__ float w2s[TT];
  float* xs = smem;
  float* gs = smem + TT * LPAD;

  const int tid  = threadIdx.x;
  const int lane = tid & 63, wave = tid >> 6;
  const int tg = lane >> 3, eg = lane & 7;  // 8 token-groups x 8 expert-groups
  const int row0 = blockIdx.x * TT;
  const int kb = wave * 64;                 // this wave's K-slice inside chunk

  float acc[4][4];
#pragma unroll
  for (int t = 0; t < 4; ++t)
#pragma unroll
    for (int e = 0; e < 4; ++e) acc[t][e] = 0.f;

  for (int kt = 0; kt < D_IN / KC; ++kt) {  // 16 chunks
    __syncthreads();
#pragma unroll
    for (int i = 0; i < 8; ++i) {           // stage x tile: 2048 f32x4
      int c = tid + i * 256;
      int tok = c >> 6, kq = c & 63;
      f32x4 v = ((const f32x4*)(x + (size_t)(row0 + tok) * D_IN + kt * KC))[kq];
      *(f32x4*)&xs[tok * LPAD + kq * 4] = v;
    }
#pragma unroll
    for (int i = 0; i < 8; ++i) {           // stage gate tile: 2048 f32x4
      int c = tid + i * 256;
      int e = c >> 6, kq = c & 63;
      f32x4 v = ((const f32x4*)(gate_w + (size_t)e * D_IN + kt * KC))[kq];
      *(f32x4*)&gs[e * LPAD + kq * 4] = v;
    }
    __syncthreads();
#pragma unroll 4
    for (int kk = 0; kk < 64; kk += 4) {
      f32x4 xv[4], gv[4];
#pragma unroll
      for (int t = 0; t < 4; ++t)
        xv[t] = *(const f32x4*)&xs[(tg * 4 + t) * LPAD + kb + kk];
#pragma unroll
      for (int e = 0; e < 4; ++e)
        gv[e] = *(const f32x4*)&gs[(eg * 4 + e) * LPAD + kb + kk];
#pragma unroll
      for (int t = 0; t < 4; ++t)
#pragma unroll
        for (int e = 0; e < 4; ++e)
#pragma unroll
          for (int m = 0; m < 4; ++m)
            acc[t][e] += xv[t][m] * gv[e][m];
    }
  }

  // cross-wave K reduction (reuse smem)
  __syncthreads();
  float* red = smem;                        // [4 waves][64 lanes][16]
#pragma unroll
  for (int t = 0; t < 4; ++t)
#pragma unroll
    for (int e = 0; e < 4; ++e)
      red[(wave * 64 + lane) * 16 + t * 4 + e] = acc[t][e];
  __syncthreads();
  float* lgt = smem + 4096;                 // [32][36] logits
  if (wave == 0) {
#pragma unroll
    for (int i = 0; i < 16; ++i) {
      float s = red[(0 * 64 + lane) * 16 + i] + red[(1 * 64 + lane) * 16 + i]
              + red[(2 * 64 + lane) * 16 + i] + red[(3 * 64 + lane) * 16 + i];
      int t = i >> 2, e = i & 3;
      lgt[(tg * 4 + t) * 36 + eg * 4 + e] = s;
    }
  }
  __syncthreads();
  if (tid < TT) {                           // top-2 per token (fp32-exact)
    float l1 = -1e30f; int e1 = 0;
    for (int e = 0; e < NE; ++e) { float v = lgt[tid * 36 + e]; if (v > l1) { l1 = v; e1 = e; } }
    float l2 = -1e30f; int e2 = 0;
    for (int e = 0; e < NE; ++e) { if (e == e1) continue; float v = lgt[tid * 36 + e]; if (v > l2) { l2 = v; e2 = e; } }
    float t = __expf(l2 - l1);
    float w2 = t / (1.f + t);
    e1s[tid] = e1; e2s[tid] = e2; w1s[tid] = 1.f - w2; w2s[tid] = w2;
  }
  __syncthreads();
#pragma unroll
  for (int i = 0; i < 4; ++i) {             // coalesced wdense write
    int c = tid + i * 256;
    int tok = c >> 5, e = c & 31;
    float v = (e == e1s[tok]) ? w1s[tok] : (e == e2s[tok]) ? w2s[tok] : 0.f;
    wdense[(size_t)(row0 + tok) * NE + e] = v;
  }
}

// ---------------------------------------------------------------------------
// Kernel 2: weight conversion to bf16 (W_cat = [base_w | lora_B], la = lora_A)
// ---------------------------------------------------------------------------
__global__ __launch_bounds__(256) void k_wconv(
    const float* __restrict__ base_w, const float* __restrict__ lora_B,
    const float* __restrict__ lora_A, u16* __restrict__ wb, u16* __restrict__ la)
{
  const int bid = blockIdx.x, tid = threadIdx.x;
  if (bid < D_OUT) {
    const float* src = base_w + (size_t)bid * D_IN;
    u16* dst = wb + (size_t)bid * KCAT;
#pragma unroll
    for (int i = 0; i < 4; ++i) {
      int c = tid + i * 256;
      f32x4 v = ((const f32x4*)src)[c];
      u16x4 h; h[0] = f2bf(v[0]); h[1] = f2bf(v[1]); h[2] = f2bf(v[2]); h[3] = f2bf(v[3]);
      ((u16x4*)dst)[c] = h;
    }
    if (tid < 128) {                        // lora_B row: 512 = 128 x float4
      f32x4 v = ((const f32x4*)(lora_B + (size_t)bid * RMOE))[tid];
      u16x4 h; h[0] = f2bf(v[0]); h[1] = f2bf(v[1]); h[2] = f2bf(v[2]); h[3] = f2bf(v[3]);
      ((u16x4*)(dst + D_IN))[tid] = h;
    }
  } else {
    int r = bid - D_OUT;                    // lora_A row 0..511
    const float* src = lora_A + (size_t)r * D_IN;
    u16* dst = la + (size_t)r * D_IN;
#pragma unroll
    for (int i = 0; i < 4; ++i) {
      int c = tid + i * 256;
      f32x4 v = ((const f32x4*)src)[c];
      u16x4 h; h[0] = f2bf(v[0]); h[1] = f2bf(v[1]); h[2] = f2bf(v[2]); h[3] = f2bf(v[3]);
      ((u16x4*)dst)[c] = h;
    }
  }
}

// ---------------------------------------------------------------------------
// Kernel 3: ax GEMM  (A_cat[:, :4096] @ lora_A^T) * w * SCALING -> A_cat tail
// m97 structure: 128x128 tile, BK=64, 4 waves (2x2), 16x16x32 bf16 MFMA
// ---------------------------------------------------------------------------
__global__ __launch_bounds__(256) void k_gemm_ax(
    const u16* __restrict__ A, const u16* __restrict__ Bw,
    const float* __restrict__ wdense, u16* __restrict__ xb)
{
  __shared__ u16 As[128 * 64];
  __shared__ u16 Bs[128 * 64];
  const int nbx = RMOE / 128;               // 4
  const int nwg = gridDim.x;                // 256 (div by 8 -> bijective swizzle)
  int bid = blockIdx.x;
  int wg = (bid & 7) * (nwg >> 3) + (bid >> 3);
  const int tm = wg / nbx, tn = wg % nbx;
  const int tid = threadIdx.x;
  const int lane = tid & 63, wave = tid >> 6;
  const int wr = wave >> 1, wc = wave & 1;

  f32x4 acc[4][4];
#pragma unroll
  for (int i = 0; i < 4; ++i)
#pragma unroll
    for (int j = 0; j < 4; ++j) acc[i][j] = (f32x4){0.f, 0.f, 0.f, 0.f};

  const int row0 = tm * 128, col0 = tn * 128;
  for (int kt = 0; kt < D_IN / 64; ++kt) {
    __syncthreads();
#pragma unroll
    for (int i = 0; i < 4; ++i) {
      int c = tid + i * 256;
      int r = c >> 3, c8 = c & 7;
      gload16(A  + (size_t)(row0 + r) * KCAT + kt * 64 + c8 * 8, &As[c * 8]);
      gload16(Bw + (size_t)(col0 + r) * D_IN + kt * 64 + c8 * 8, &Bs[c * 8]);
    }
    __syncthreads();
#pragma unroll
    for (int kk = 0; kk < 2; ++kk) {
      bf16x8 af[4], bfr[4];
      int ko = kk * 32 + (lane >> 4) * 8;
#pragma unroll
      for (int i = 0; i < 4; ++i) {
        af[i]  = *(const bf16x8*)&As[(wr * 64 + i * 16 + (lane & 15)) * 64 + ko];
        bfr[i] = *(const bf16x8*)&Bs[(wc * 64 + i * 16 + (lane & 15)) * 64 + ko];
      }
#pragma unroll
      for (int i = 0; i < 4; ++i)
#pragma unroll
        for (int j = 0; j < 4; ++j)
          acc[i][j] = __builtin_amdgcn_mfma_f32_16x16x32_bf16(af[i], bfr[j], acc[i][j], 0, 0, 0);
    }
  }
  // epilogue: scale by gate weight, SCALING, store bf16 to A_cat tail
#pragma unroll
  for (int i = 0; i < 4; ++i) {
    int rbase = row0 + wr * 64 + i * 16 + ((lane >> 4) << 2);
#pragma unroll
    for (int j = 0; j < 4; ++j) {
      int cb = col0 + wc * 64 + j * 16 + (lane & 15);
#pragma unroll
      for (int q = 0; q < 4; ++q) {
        int trow = rbase + q;
        float wgt = wdense[(size_t)trow * NE + (cb >> 4)];
        xb[(size_t)trow * KCAT + D_IN + cb] = f2bf(acc[i][j][q] * wgt * SCALING);
      }
    }
  }
}

// ---------------------------------------------------------------------------
// Kernel 4: main GEMM  out = A_cat @ W_cat^T   (M=8192, N=4096, K=4608)
// ---------------------------------------------------------------------------
__global__ __launch_bounds__(256) void k_gemm_main(
    const u16* __restrict__ A, const u16* __restrict__ Bw, float* __restrict__ C)
{
  __shared__ u16 As[128 * 64];
  __shared__ u16 Bs[128 * 64];
  const int nbx = D_OUT / 128;              // 32
  const int nwg = gridDim.x;                // 2048 (div by 8)
  int bid = blockIdx.x;
  int wg = (bid & 7) * (nwg >> 3) + (bid >> 3);
  const int tm = wg / nbx, tn = wg % nbx;
  const int tid = threadIdx.x;
  const int lane = tid & 63, wave = tid >> 6;
  const int wr = wave >> 1, wc = wave & 1;

  f32x4 acc[4][4];
#pragma unroll
  for (int i = 0; i < 4; ++i)
#pragma unroll
    for (int j = 0; j < 4; ++j) acc[i][j] = (f32x4){0.f, 0.f, 0.f, 0.f};

  const int row0 = tm * 128, col0 = tn * 128;
  for (int kt = 0; kt < KCAT / 64; ++kt) {  // 72 iters
    __syncthreads();
#pragma unroll
    for (int i = 0; i < 4; ++i) {
      int c = tid + i * 256;
      int r = c >> 3, c8 = c & 7;
      gload16(A  + (size_t)(row0 + r) * KCAT + kt * 64 + c8 * 8, &As[c * 8]);
      gload16(Bw + (size_t)(col0 + r) * KCAT + kt * 64 + c8 * 8, &Bs[c * 8]);
    }
    __syncthreads();
#pragma unroll
    for (int kk = 0; kk < 2; ++kk) {
      bf16x8 af[4], bfr[4];
      int ko = kk * 32 + (lane >> 4) * 8;
#pragma unroll
      for (int i = 0; i < 4; ++i) {
        af[i]  = *(const bf16x8*)&As[(wr * 64 + i * 16 + (lane & 15)) * 64 + ko];
        bfr[i] = *(const bf16x8*)&Bs[(wc * 64 + i * 16 + (lane & 15)) * 64 + ko];
      }
#pragma unroll
      for (int i = 0; i < 4; ++i)
#pragma unroll
        for (int j = 0; j < 4; ++j)
          acc[i][j] = __builtin_amdgcn_mfma_f32_16x16x32_bf16(af[i], bfr[j], acc[i][j], 0, 0, 0);
    }
  }
#pragma unroll
  for (int i = 0; i < 4; ++i) {
    int rbase = row0 + wr * 64 + i * 16 + ((lane >> 4) << 2);
#pragma unroll
    for (int j = 0; j < 4; ++j) {
      int cb = col0 + wc * 64 + j * 16 + (lane & 15);
#pragma unroll
      for (int q = 0; q < 4; ++q)
        C[(size_t)(rbase + q) * D_OUT + cb] = acc[i][j][q];
    }
  }
}

// ---------------------------------------------------------------------------
extern "C" void kernel_launch(void* const* d_in, const int* in_sizes, int n_in,
                              void* d_out, int out_size, void* d_ws, size_t ws_size,
                              hipStream_t stream) {
  const float* x      = (const float*)d_in[0];
  const float* base_w = (const float*)d_in[1];
  const float* gate_w = (const float*)d_in[2];
  const float* lora_A = (const float*)d_in[3];
  const float* lora_B = (const float*)d_in[4];
  float* out = (float*)d_out;

  char* ws = (char*)d_ws;
  u16* xb       = (u16*)ws;                                    // 8192*4608*2 = 75,497,472 B
  u16* wb       = (u16*)(ws + 75497472);                       // 4096*4608*2 = 37,748,736 B
  u16* la       = (u16*)(ws + 75497472 + 37748736);            //  512*4096*2 =  4,194,304 B
  float* wdense = (float*)(ws + 75497472 + 37748736 + 4194304); // 8192*32*4  =  1,048,576 B

  hipLaunchKernelGGL(k_conv_x,    dim3(NTOK),         dim3(256), 0, stream, x, xb);
  hipLaunchKernelGGL(k_logits,    dim3(NTOK / TT),    dim3(256), 0, stream, x, gate_w, wdense);
  hipLaunchKernelGGL(k_wconv,     dim3(D_OUT + RMOE), dim3(256), 0, stream, base_w, lora_B, lora_A, wb, la);
  hipLaunchKernelGGL(k_gemm_ax,   dim3((NTOK/128) * (RMOE/128)),  dim3(256), 0, stream, xb, la, wdense, xb);
  hipLaunchKernelGGL(k_gemm_main, dim3((NTOK/128) * (D_OUT/128)), dim3(256), 0, stream, xb, wb, out);
}

// Round 3
// 435.175 us; speedup vs baseline: 2.5447x; 1.5346x over previous
//
#include <hip/hip_runtime.h>

// MoE-LoRA linear, MI355X (gfx950).
// out = x @ base_w^T + 2.0 * ((x @ lora_A^T) * topk_gate_w) @ lora_B^T
// A_cat[8192][4608] = [ bf16(x) | bf16(SCALING * w_e * (x . lora_A_row)) ]
// W_cat[4096][4608] = [ bf16(base_w) | bf16(lora_B) ]
// out = A_cat @ W_cat^T  via 256x256-tile 8-wave 4-phase counted-vmcnt GEMM
// (m201-style: T1 XCD swizzle + T2 LDS XOR swizzle + T3/T4 phased counted
//  vmcnt + T5 setprio).

#define D_IN   4096
#define D_OUT  4096
#define NTOK   8192      // B*S
#define NE     32
#define RMOE   512       // E*R
#define KCAT   4608      // D_IN + RMOE
#define SCALING 2.0f

typedef unsigned short u16;
typedef __attribute__((ext_vector_type(4))) float  f32x4;
typedef __attribute__((ext_vector_type(4))) unsigned short u16x4;
typedef __attribute__((ext_vector_type(8))) short  bf16x8;

__device__ __forceinline__ u16 f2bf(float f) {
  unsigned u = __float_as_uint(f);
  u += 0x7FFFu + ((u >> 16) & 1u);        // round-to-nearest-even
  return (u16)(u >> 16);
}

__device__ __forceinline__ void gload16(const void* g, void* l) {
  __builtin_amdgcn_global_load_lds(
      (const __attribute__((address_space(1))) unsigned*)g,
      (__attribute__((address_space(3))) unsigned*)l, 16, 0, 0);
}

#define BAR() do { asm volatile("" ::: "memory"); \
                   __builtin_amdgcn_s_barrier();  \
                   asm volatile("" ::: "memory"); } while (0)
#define WAITV4() asm volatile("s_waitcnt vmcnt(4)" ::: "memory")
#define WAITV0() asm volatile("s_waitcnt vmcnt(0)" ::: "memory")

// ---------------------------------------------------------------------------
// Kernel 1: gating logits (fp32 tiled GEMM) + top-2 + renorm -> wdense
//           fused with x -> bf16 conversion into A_cat[:, 0:4096].
// ---------------------------------------------------------------------------
#define TT 32
#define KC 256
#define LPAD (KC + 4)

__global__ __launch_bounds__(256) void k_logits(
    const float* __restrict__ x, const float* __restrict__ gate_w,
    float* __restrict__ wdense, u16* __restrict__ xb)
{
  __shared__ float smem[2 * TT * LPAD];     // xs | gs  (66,560 B)
  __shared__ int   e1s[TT]; __shared__ int   e2s[TT];
  __shared__ float w1s[TT]; __shared__ float w2s[TT];
  float* xs = smem;
  float* gs = smem + TT * LPAD;

  const int tid  = threadIdx.x;
  const int lane = tid & 63, wave = tid >> 6;
  const int tg = lane >> 3, eg = lane & 7;  // 8 token-groups x 8 expert-groups
  const int row0 = blockIdx.x * TT;
  const int kb = wave * 64;                 // this wave's K-slice inside chunk

  float acc[4][4];
#pragma unroll
  for (int t = 0; t < 4; ++t)
#pragma unroll
    for (int e = 0; e < 4; ++e) acc[t][e] = 0.f;

  for (int kt = 0; kt < D_IN / KC; ++kt) {  // 16 chunks
    __syncthreads();
#pragma unroll
    for (int i = 0; i < 8; ++i) {           // stage x tile + emit bf16 copy
      int c = tid + i * 256;
      int tok = c >> 6, kq = c & 63;
      f32x4 v = ((const f32x4*)(x + (size_t)(row0 + tok) * D_IN + kt * KC))[kq];
      *(f32x4*)&xs[tok * LPAD + kq * 4] = v;
      u16x4 h;
      h[0] = f2bf(v[0]); h[1] = f2bf(v[1]); h[2] = f2bf(v[2]); h[3] = f2bf(v[3]);
      ((u16x4*)(xb + (size_t)(row0 + tok) * KCAT + kt * KC))[kq] = h;
    }
#pragma unroll
    for (int i = 0; i < 8; ++i) {           // stage gate tile: 2048 f32x4
      int c = tid + i * 256;
      int e = c >> 6, kq = c & 63;
      f32x4 v = ((const f32x4*)(gate_w + (size_t)e * D_IN + kt * KC))[kq];
      *(f32x4*)&gs[e * LPAD + kq * 4] = v;
    }
    __syncthreads();
#pragma unroll 4
    for (int kk = 0; kk < 64; kk += 4) {
      f32x4 xv[4], gv[4];
#pragma unroll
      for (int t = 0; t < 4; ++t)
        xv[t] = *(const f32x4*)&xs[(tg * 4 + t) * LPAD + kb + kk];
#pragma unroll
      for (int e = 0; e < 4; ++e)
        gv[e] = *(const f32x4*)&gs[(eg * 4 + e) * LPAD + kb + kk];
#pragma unroll
      for (int t = 0; t < 4; ++t)
#pragma unroll
        for (int e = 0; e < 4; ++e)
#pragma unroll
          for (int m = 0; m < 4; ++m)
            acc[t][e] += xv[t][m] * gv[e][m];
    }
  }

  // cross-wave K reduction (reuse smem)
  __syncthreads();
  float* red = smem;                        // [4 waves][64 lanes][16]
#pragma unroll
  for (int t = 0; t < 4; ++t)
#pragma unroll
    for (int e = 0; e < 4; ++e)
      red[(wave * 64 + lane) * 16 + t * 4 + e] = acc[t][e];
  __syncthreads();
  float* lgt = smem + 4096;                 // [32][36] logits
  if (wave == 0) {
#pragma unroll
    for (int i = 0; i < 16; ++i) {
      float s = red[(0 * 64 + lane) * 16 + i] + red[(1 * 64 + lane) * 16 + i]
              + red[(2 * 64 + lane) * 16 + i] + red[(3 * 64 + lane) * 16 + i];
      int t = i >> 2, e = i & 3;
      lgt[(tg * 4 + t) * 36 + eg * 4 + e] = s;
    }
  }
  __syncthreads();
  if (tid < TT) {                           // top-2 per token (fp32-exact)
    float l1 = -1e30f; int e1 = 0;
    for (int e = 0; e < NE; ++e) { float v = lgt[tid * 36 + e]; if (v > l1) { l1 = v; e1 = e; } }
    float l2 = -1e30f; int e2 = 0;
    for (int e = 0; e < NE; ++e) { if (e == e1) continue; float v = lgt[tid * 36 + e]; if (v > l2) { l2 = v; e2 = e; } }
    float t = __expf(l2 - l1);
    float w2 = t / (1.f + t);
    e1s[tid] = e1; e2s[tid] = e2; w1s[tid] = 1.f - w2; w2s[tid] = w2;
  }
  __syncthreads();
#pragma unroll
  for (int i = 0; i < 4; ++i) {             // coalesced wdense write
    int c = tid + i * 256;
    int tok = c >> 5, e = c & 31;
    float v = (e == e1s[tok]) ? w1s[tok] : (e == e2s[tok]) ? w2s[tok] : 0.f;
    wdense[(size_t)(row0 + tok) * NE + e] = v;
  }
}

// ---------------------------------------------------------------------------
// Kernel 2: weight conversion to bf16 (W_cat = [base_w | lora_B], la = lora_A)
// ---------------------------------------------------------------------------
__global__ __launch_bounds__(256) void k_wconv(
    const float* __restrict__ base_w, const float* __restrict__ lora_B,
    const float* __restrict__ lora_A, u16* __restrict__ wb, u16* __restrict__ la)
{
  const int bid = blockIdx.x, tid = threadIdx.x;
  if (bid < D_OUT) {
    const float* src = base_w + (size_t)bid * D_IN;
    u16* dst = wb + (size_t)bid * KCAT;
#pragma unroll
    for (int i = 0; i < 4; ++i) {
      int c = tid + i * 256;
      f32x4 v = ((const f32x4*)src)[c];
      u16x4 h; h[0] = f2bf(v[0]); h[1] = f2bf(v[1]); h[2] = f2bf(v[2]); h[3] = f2bf(v[3]);
      ((u16x4*)dst)[c] = h;
    }
    if (tid < 128) {                        // lora_B row: 512 = 128 x float4
      f32x4 v = ((const f32x4*)(lora_B + (size_t)bid * RMOE))[tid];
      u16x4 h; h[0] = f2bf(v[0]); h[1] = f2bf(v[1]); h[2] = f2bf(v[2]); h[3] = f2bf(v[3]);
      ((u16x4*)(dst + D_IN))[tid] = h;
    }
  } else {
    int r = bid - D_OUT;                    // lora_A row 0..511
    const float* src = lora_A + (size_t)r * D_IN;
    u16* dst = la + (size_t)r * D_IN;
#pragma unroll
    for (int i = 0; i < 4; ++i) {
      int c = tid + i * 256;
      f32x4 v = ((const f32x4*)src)[c];
      u16x4 h; h[0] = f2bf(v[0]); h[1] = f2bf(v[1]); h[2] = f2bf(v[2]); h[3] = f2bf(v[3]);
      ((u16x4*)dst)[c] = h;
    }
  }
}

// ---------------------------------------------------------------------------
// Kernel 3: ax GEMM  (A_cat[:, :4096] @ lora_A^T) * w * SCALING -> A_cat tail
// 128x128 tile, BK=64, 4 waves (2x2), 16x16x32 bf16 MFMA  (N=512 too narrow
// for 256^2 tiles).
// ---------------------------------------------------------------------------
__global__ __launch_bounds__(256) void k_gemm_ax(
    const u16* __restrict__ A, const u16* __restrict__ Bw,
    const float* __restrict__ wdense, u16* __restrict__ xb)
{
  __shared__ u16 As[128 * 64];
  __shared__ u16 Bs[128 * 64];
  const int nbx = RMOE / 128;               // 4
  const int nwg = gridDim.x;                // 256 (div by 8 -> bijective swizzle)
  int bid = blockIdx.x;
  int wg = (bid & 7) * (nwg >> 3) + (bid >> 3);
  const int tm = wg / nbx, tn = wg % nbx;
  const int tid = threadIdx.x;
  const int lane = tid & 63, wave = tid >> 6;
  const int wr = wave >> 1, wc = wave & 1;

  f32x4 acc[4][4];
#pragma unroll
  for (int i = 0; i < 4; ++i)
#pragma unroll
    for (int j = 0; j < 4; ++j) acc[i][j] = (f32x4){0.f, 0.f, 0.f, 0.f};

  const int row0 = tm * 128, col0 = tn * 128;
  for (int kt = 0; kt < D_IN / 64; ++kt) {
    __syncthreads();
#pragma unroll
    for (int i = 0; i < 4; ++i) {
      int c = tid + i * 256;
      int r = c >> 3, c8 = c & 7;
      gload16(A  + (size_t)(row0 + r) * KCAT + kt * 64 + c8 * 8, &As[c * 8]);
      gload16(Bw + (size_t)(col0 + r) * D_IN + kt * 64 + c8 * 8, &Bs[c * 8]);
    }
    __syncthreads();
#pragma unroll
    for (int kk = 0; kk < 2; ++kk) {
      bf16x8 af[4], bfr[4];
      int ko = kk * 32 + (lane >> 4) * 8;
#pragma unroll
      for (int i = 0; i < 4; ++i) {
        af[i]  = *(const bf16x8*)&As[(wr * 64 + i * 16 + (lane & 15)) * 64 + ko];
        bfr[i] = *(const bf16x8*)&Bs[(wc * 64 + i * 16 + (lane & 15)) * 64 + ko];
      }
#pragma unroll
      for (int i = 0; i < 4; ++i)
#pragma unroll
        for (int j = 0; j < 4; ++j)
          acc[i][j] = __builtin_amdgcn_mfma_f32_16x16x32_bf16(af[i], bfr[j], acc[i][j], 0, 0, 0);
    }
  }
#pragma unroll
  for (int i = 0; i < 4; ++i) {
    int rbase = row0 + wr * 64 + i * 16 + ((lane >> 4) << 2);
#pragma unroll
    for (int j = 0; j < 4; ++j) {
      int cb = col0 + wc * 64 + j * 16 + (lane & 15);
#pragma unroll
      for (int q = 0; q < 4; ++q) {
        int trow = rbase + q;
        float wgt = wdense[(size_t)trow * NE + (cb >> 4)];
        xb[(size_t)trow * KCAT + D_IN + cb] = f2bf(acc[i][j][q] * wgt * SCALING);
      }
    }
  }
}

// ---------------------------------------------------------------------------
// Kernel 4: main GEMM  out = A_cat @ W_cat^T  (M=8192, N=4096, K=4608)
// 256x256 tile, 8 waves (2Mx4N), BK=64, double-buffered 128 KiB LDS,
// 4 phases/K-tile, counted vmcnt(4) once per tile, XOR-swizzled LDS reads
// with pre-swizzled global sources (linear gload_lds dests).
// ---------------------------------------------------------------------------
#define NT (KCAT / 64)    // 72

__global__ __launch_bounds__(512, 2) void k_gemm_main(
    const u16* __restrict__ A, const u16* __restrict__ Bw, float* __restrict__ C)
{
  // [buf:2][op:2][half:2][128 rows][64 cols] u16  = 128 KiB
  __shared__ u16 sh[65536];

  const int tid  = threadIdx.x;
  const int lane = tid & 63;
  const int wv   = tid >> 6;            // 0..7
  const int wm   = wv >> 2;             // 0..1
  const int wn   = wv & 3;              // 0..3
  const int l15  = lane & 15, g = lane >> 4;

  // T1: bijective XCD swizzle (512 blocks, 512 % 8 == 0)
  const int nwg = gridDim.x;
  int bid = blockIdx.x;
  int wg = (bid & 7) * (nwg >> 3) + (bid >> 3);
  const int tn = wg & 15, tm = wg >> 4; // 16 n-tiles, 32 m-tiles

  // ---- LDS read addressing (T2 swizzle: slot ^= row&7; row&7 == l15&7) ----
  const int rsw   = (g ^ (l15 & 7)) * 8;          // swizzled 16B-slot, elems
  const int aBase = l15 * 64 + rsw;               // within A-half (+mf*1024)
  const int bBase = ((wn & 1) * 64 + l15) * 64 + rsw;

  // ---- staging pointers: pre-swizzled global sources -----------------------
  const int c0 = tid, c1 = tid + 512;
  const int r0s = c0 >> 3, s0s = (c0 & 7) ^ (r0s & 7);
  const int r1s = c1 >> 3, s1s = (c1 & 7) ^ (r1s & 7);
  const size_t offc0 = (size_t)r0s * KCAT + s0s * 8;
  const size_t offc1 = (size_t)r1s * KCAT + s1s * 8;
  const u16* pA0a = A  + (size_t)(tm * 256 +   0) * KCAT + offc0;
  const u16* pA0b = A  + (size_t)(tm * 256 +   0) * KCAT + offc1;
  const u16* pA1a = A  + (size_t)(tm * 256 + 128) * KCAT + offc0;
  const u16* pA1b = A  + (size_t)(tm * 256 + 128) * KCAT + offc1;
  const u16* pB0a = Bw + (size_t)(tn * 256 +   0) * KCAT + offc0;
  const u16* pB0b = Bw + (size_t)(tn * 256 +   0) * KCAT + offc1;
  const u16* pB1a = Bw + (size_t)(tn * 256 + 128) * KCAT + offc0;
  const u16* pB1b = Bw + (size_t)(tn * 256 + 128) * KCAT + offc1;
  const int d0 = c0 * 8, d1 = c1 * 8;   // linear LDS dest chunks (elems)

#define STG(pa, pb, base) do { \
    gload16((pa), &sh[(base) + d0]); \
    gload16((pb), &sh[(base) + d1]); \
    (pa) += 64; (pb) += 64; } while (0)

  f32x4 acc[8][4];
#pragma unroll
  for (int i = 0; i < 8; ++i)
#pragma unroll
    for (int j = 0; j < 4; ++j) acc[i][j] = (f32x4){0.f, 0.f, 0.f, 0.f};

  // ---- prologue: tile0 (all 4 halves) + tile1 (A0,B0) ----------------------
  STG(pA0a, pA0b,     0);      // A0(0) -> buf0
  STG(pB0a, pB0b, 16384);      // B0(0)
  STG(pA1a, pA1b,  8192);      // A1(0)
  STG(pB1a, pB1b, 24576);      // B1(0)
  STG(pA0a, pA0b, 32768 +     0);  // A0(1) -> buf1
  STG(pB0a, pB0b, 32768 + 16384);  // B0(1)
  WAITV4();                    // tile0 fully landed; A0(1),B0(1) in flight
  BAR();

  bf16x8 aLo[4][2], aHi[4][2], bR[2][2];

  for (int u = 0; u < NT; ++u) {
    const int cb = (u & 1) << 15;       // compute buffer base (elems)
    const int nb = cb ^ 32768;          // next buffer
    const int shA = cb + (wm << 13);            // this wave's A-half
    const int shB = cb + 16384 + ((wn >> 1) << 13);

    // ---- P1: stage A1(u+1); read aLo(mf0-3)+bR(n0-1); MFMA [0-3][0-1] ----
    if (u < NT - 1) STG(pA1a, pA1b, nb + 8192);
#pragma unroll
    for (int m = 0; m < 4; ++m) {
      int ix = shA + aBase + m * 1024;
      aLo[m][0] = *(const bf16x8*)&sh[ix];
      aLo[m][1] = *(const bf16x8*)&sh[ix ^ 32];
    }
#pragma unroll
    for (int n = 0; n < 2; ++n) {
      int ix = shB + bBase + n * 1024;
      bR[n][0] = *(const bf16x8*)&sh[ix];
      bR[n][1] = *(const bf16x8*)&sh[ix ^ 32];
    }
    BAR();
    __builtin_amdgcn_s_setprio(1);
#pragma unroll
    for (int m = 0; m < 4; ++m)
#pragma unroll
      for (int n = 0; n < 2; ++n)
#pragma unroll
        for (int kk = 0; kk < 2; ++kk)
          acc[m][n] = __builtin_amdgcn_mfma_f32_16x16x32_bf16(aLo[m][kk], bR[n][kk], acc[m][n], 0, 0, 0);
    __builtin_amdgcn_s_setprio(0);
    BAR();

    // ---- P2: stage B1(u+1); read aHi(mf4-7); MFMA [4-7][0-1] -------------
    if (u < NT - 1) STG(pB1a, pB1b, nb + 24576);
#pragma unroll
    for (int m = 0; m < 4; ++m) {
      int ix = shA + aBase + (m + 4) * 1024;
      aHi[m][0] = *(const bf16x8*)&sh[ix];
      aHi[m][1] = *(const bf16x8*)&sh[ix ^ 32];
    }
    BAR();
    __builtin_amdgcn_s_setprio(1);
#pragma unroll
    for (int m = 0; m < 4; ++m)
#pragma unroll
      for (int n = 0; n < 2; ++n)
#pragma unroll
        for (int kk = 0; kk < 2; ++kk)
          acc[m + 4][n] = __builtin_amdgcn_mfma_f32_16x16x32_bf16(aHi[m][kk], bR[n][kk], acc[m + 4][n], 0, 0, 0);
    __builtin_amdgcn_s_setprio(0);
    BAR();

    // ---- P3: stage A0(u+2); read bR(n2-3); MFMA [4-7][2-3] ---------------
    if (u < NT - 2) STG(pA0a, pA0b, cb + 0);
#pragma unroll
    for (int n = 0; n < 2; ++n) {
      int ix = shB + bBase + (n + 2) * 1024;
      bR[n][0] = *(const bf16x8*)&sh[ix];
      bR[n][1] = *(const bf16x8*)&sh[ix ^ 32];
    }
    BAR();
    __builtin_amdgcn_s_setprio(1);
#pragma unroll
    for (int m = 0; m < 4; ++m)
#pragma unroll
      for (int n = 0; n < 2; ++n)
#pragma unroll
        for (int kk = 0; kk < 2; ++kk)
          acc[m + 4][n + 2] = __builtin_amdgcn_mfma_f32_16x16x32_bf16(aHi[m][kk], bR[n][kk], acc[m + 4][n + 2], 0, 0, 0);
    __builtin_amdgcn_s_setprio(0);
    BAR();

    // ---- P4: stage B0(u+2); no reads; counted wait; MFMA [0-3][2-3] ------
    if (u < NT - 2) { STG(pB0a, pB0b, cb + 16384); WAITV4(); }
    else            { WAITV0(); }
    BAR();
    __builtin_amdgcn_s_setprio(1);
#pragma unroll
    for (int m = 0; m < 4; ++m)
#pragma unroll
      for (int n = 0; n < 2; ++n)
#pragma unroll
        for (int kk = 0; kk < 2; ++kk)
          acc[m][n + 2] = __builtin_amdgcn_mfma_f32_16x16x32_bf16(aLo[m][kk], bR[n][kk], acc[m][n + 2], 0, 0, 0);
    __builtin_amdgcn_s_setprio(0);
    BAR();
  }
#undef STG

  // ---- epilogue -------------------------------------------------------------
  const int crow0 = tm * 256 + wm * 128 + g * 4;
  const int ccol0 = tn * 256 + wn * 64 + l15;
#pragma unroll
  for (int mf = 0; mf < 8; ++mf)
#pragma unroll
    for (int n = 0; n < 4; ++n)
#pragma unroll
      for (int q = 0; q < 4; ++q)
        C[(size_t)(crow0 + mf * 16 + q) * D_OUT + ccol0 + n * 16] = acc[mf][n][q];
}

// ---------------------------------------------------------------------------
extern "C" void kernel_launch(void* const* d_in, const int* in_sizes, int n_in,
                              void* d_out, int out_size, void* d_ws, size_t ws_size,
                              hipStream_t stream) {
  const float* x      = (const float*)d_in[0];
  const float* base_w = (const float*)d_in[1];
  const float* gate_w = (const float*)d_in[2];
  const float* lora_A = (const float*)d_in[3];
  const float* lora_B = (const float*)d_in[4];
  float* out = (float*)d_out;

  char* ws = (char*)d_ws;
  u16* xb       = (u16*)ws;                                     // 75,497,472 B
  u16* wb       = (u16*)(ws + 75497472);                        // 37,748,736 B
  u16* la       = (u16*)(ws + 75497472 + 37748736);             //  4,194,304 B
  float* wdense = (float*)(ws + 75497472 + 37748736 + 4194304); //  1,048,576 B

  hipLaunchKernelGGL(k_logits,    dim3(NTOK / TT),    dim3(256), 0, stream, x, gate_w, wdense, xb);
  hipLaunchKernelGGL(k_wconv,     dim3(D_OUT + RMOE), dim3(256), 0, stream, base_w, lora_B, lora_A, wb, la);
  hipLaunchKernelGGL(k_gemm_ax,   dim3((NTOK/128) * (RMOE/128)),  dim3(256), 0, stream, xb, la, wdense, xb);
  hipLaunchKernelGGL(k_gemm_main, dim3((NTOK/256) * (D_OUT/256)), dim3(512), 0, stream, xb, wb, out);
}

// Round 4
// 384.272 us; speedup vs baseline: 2.8818x; 1.1325x over previous
//
#include <hip/hip_runtime.h>

// MoE-LoRA linear, MI355X (gfx950).
// out = x @ base_w^T + 2.0 * ((x @ lora_A^T) * topk_gate_w) @ lora_B^T
// A_cat[8192][4608] = [ bf16(x) | bf16(SCALING * w_e * (x . lora_A_row)) ]
// W_cat[4096][4608] = [ bf16(base_w) | bf16(lora_B) ]
// out = A_cat @ W_cat^T  via 256x256-tile 8-wave 4-phase counted-vmcnt GEMM
// with one-phase-ahead LDS fragment reads (reads land a full phase before use).

#define D_IN   4096
#define D_OUT  4096
#define NTOK   8192      // B*S
#define NE     32
#define RMOE   512       // E*R
#define KCAT   4608      // D_IN + RMOE
#define SCALING 2.0f

typedef unsigned short u16;
typedef __attribute__((ext_vector_type(4))) float  f32x4;
typedef __attribute__((ext_vector_type(4))) unsigned short u16x4;
typedef __attribute__((ext_vector_type(8))) short  bf16x8;

__device__ __forceinline__ u16 f2bf(float f) {
  unsigned u = __float_as_uint(f);
  u += 0x7FFFu + ((u >> 16) & 1u);        // round-to-nearest-even
  return (u16)(u >> 16);
}

__device__ __forceinline__ void gload16(const void* g, void* l) {
  __builtin_amdgcn_global_load_lds(
      (const __attribute__((address_space(1))) unsigned*)g,
      (__attribute__((address_space(3))) unsigned*)l, 16, 0, 0);
}

#define BAR() do { asm volatile("" ::: "memory"); \
                   __builtin_amdgcn_s_barrier();  \
                   asm volatile("" ::: "memory"); } while (0)
#define WAITV8() asm volatile("s_waitcnt vmcnt(8)" ::: "memory")
#define WAITV4() asm volatile("s_waitcnt vmcnt(4)" ::: "memory")
#define WAITV0() asm volatile("s_waitcnt vmcnt(0)" ::: "memory")

// ---------------------------------------------------------------------------
// Kernel 1: gating logits (fp32 tiled GEMM) + top-2 + renorm -> wdense,
//           fused with x -> bf16 conversion into A_cat[:, 0:4096].
// 8 tok x 8 exp register tile per thread; chunk-XOR LDS swizzle (2-way max).
// ---------------------------------------------------------------------------
#define TT 32
#define KC 256

__global__ __launch_bounds__(256) void k_logits(
    const float* __restrict__ x, const float* __restrict__ gate_w,
    float* __restrict__ wdense, u16* __restrict__ xb)
{
  __shared__ float smem[2 * TT * KC];       // xs | gs  (64 KiB)
  __shared__ float lgt[TT * 36];
  __shared__ int   e1s[TT]; __shared__ int   e2s[TT];
  __shared__ float w1s[TT]; __shared__ float w2s[TT];
  float* xs = smem;
  float* gs = smem + TT * KC;

  const int tid  = threadIdx.x;
  const int lane = tid & 63, wave = tid >> 6;
  const int ks = lane >> 4, tg = (lane >> 2) & 3, eg = lane & 3;
  const int row0 = blockIdx.x * TT;
  const int kc0 = wave * 16 + ks * 4;       // thread's first chunk (of 64/tile)

  float acc[8][8];
#pragma unroll
  for (int t = 0; t < 8; ++t)
#pragma unroll
    for (int e = 0; e < 8; ++e) acc[t][e] = 0.f;

  for (int kt = 0; kt < D_IN / KC; ++kt) {  // 16 tile-chunks
    __syncthreads();
#pragma unroll
    for (int i = 0; i < 8; ++i) {           // stage x tile + emit bf16 copy
      int c = tid + i * 256;
      int tok = c >> 6, kq = c & 63;
      f32x4 v = ((const f32x4*)(x + (size_t)(row0 + tok) * D_IN + kt * KC))[kq];
      *(f32x4*)&xs[tok * KC + ((kq ^ (tok >> 3)) << 2)] = v;
      u16x4 h;
      h[0] = f2bf(v[0]); h[1] = f2bf(v[1]); h[2] = f2bf(v[2]); h[3] = f2bf(v[3]);
      ((u16x4*)(xb + (size_t)(row0 + tok) * KCAT + kt * KC))[kq] = h;
    }
#pragma unroll
    for (int i = 0; i < 8; ++i) {           // stage gate tile
      int c = tid + i * 256;
      int e = c >> 6, kq = c & 63;
      f32x4 v = ((const f32x4*)(gate_w + (size_t)e * D_IN + kt * KC))[kq];
      *(f32x4*)&gs[e * KC + ((kq ^ (e >> 3)) << 2)] = v;
    }
    __syncthreads();
#pragma unroll
    for (int j = 0; j < 4; ++j) {
      const int Kc = kc0 + j;
      f32x4 xv[8], gv[8];
#pragma unroll
      for (int t = 0; t < 8; ++t)
        xv[t] = *(const f32x4*)&xs[(tg * 8 + t) * KC + ((Kc ^ tg) << 2)];
#pragma unroll
      for (int e = 0; e < 8; ++e)
        gv[e] = *(const f32x4*)&gs[(eg * 8 + e) * KC + ((Kc ^ eg) << 2)];
#pragma unroll
      for (int t = 0; t < 8; ++t)
#pragma unroll
        for (int e = 0; e < 8; ++e)
#pragma unroll
          for (int m = 0; m < 4; ++m)
            acc[t][e] += xv[t][m] * gv[e][m];
    }
  }

  // reduce over ks (lane bits 4-5)
#pragma unroll
  for (int t = 0; t < 8; ++t)
#pragma unroll
    for (int e = 0; e < 8; ++e) {
      float v = acc[t][e];
      v += __shfl_xor(v, 16);
      v += __shfl_xor(v, 32);
      acc[t][e] = v;
    }
  __syncthreads();                          // xs area reused below
  float* red = smem;                        // [4 waves][16 groups][64]
  if (ks == 0) {
#pragma unroll
    for (int t = 0; t < 8; ++t)
#pragma unroll
      for (int e4 = 0; e4 < 8; e4 += 4) {
        f32x4 v = { acc[t][e4], acc[t][e4 + 1], acc[t][e4 + 2], acc[t][e4 + 3] };
        *(f32x4*)&red[(wave * 16 + tg * 4 + eg) * 64 + t * 8 + e4] = v;
      }
  }
  __syncthreads();
  {                                         // final 4-way wave reduction
    int tok = tid >> 3, e4 = (tid & 7) << 2;
    f32x4 s = {0.f, 0.f, 0.f, 0.f};
#pragma unroll
    for (int w = 0; w < 4; ++w)
      s += *(const f32x4*)&red[(w * 16 + (tok >> 3) * 4 + (e4 >> 3)) * 64 + (tok & 7) * 8 + (e4 & 7)];
    *(f32x4*)&lgt[tok * 36 + e4] = s;
  }
  __syncthreads();
  if (tid < TT) {                           // top-2 per token (fp32-exact)
    float l1 = -1e30f; int e1 = 0;
    for (int e = 0; e < NE; ++e) { float v = lgt[tid * 36 + e]; if (v > l1) { l1 = v; e1 = e; } }
    float l2 = -1e30f; int e2 = 0;
    for (int e = 0; e < NE; ++e) { if (e == e1) continue; float v = lgt[tid * 36 + e]; if (v > l2) { l2 = v; e2 = e; } }
    float t = __expf(l2 - l1);
    float w2 = t / (1.f + t);
    e1s[tid] = e1; e2s[tid] = e2; w1s[tid] = 1.f - w2; w2s[tid] = w2;
  }
  __syncthreads();
#pragma unroll
  for (int i = 0; i < 4; ++i) {             // coalesced wdense write
    int c = tid + i * 256;
    int tok = c >> 5, e = c & 31;
    float v = (e == e1s[tok]) ? w1s[tok] : (e == e2s[tok]) ? w2s[tok] : 0.f;
    wdense[(size_t)(row0 + tok) * NE + e] = v;
  }
}

// ---------------------------------------------------------------------------
// Kernel 2: weight conversion to bf16 (W_cat = [base_w | lora_B], la = lora_A)
// ---------------------------------------------------------------------------
__global__ __launch_bounds__(256) void k_wconv(
    const float* __restrict__ base_w, const float* __restrict__ lora_B,
    const float* __restrict__ lora_A, u16* __restrict__ wb, u16* __restrict__ la)
{
  const int bid = blockIdx.x, tid = threadIdx.x;
  if (bid < D_OUT) {
    const float* src = base_w + (size_t)bid * D_IN;
    u16* dst = wb + (size_t)bid * KCAT;
#pragma unroll
    for (int i = 0; i < 4; ++i) {
      int c = tid + i * 256;
      f32x4 v = ((const f32x4*)src)[c];
      u16x4 h; h[0] = f2bf(v[0]); h[1] = f2bf(v[1]); h[2] = f2bf(v[2]); h[3] = f2bf(v[3]);
      ((u16x4*)dst)[c] = h;
    }
    if (tid < 128) {                        // lora_B row: 512 = 128 x float4
      f32x4 v = ((const f32x4*)(lora_B + (size_t)bid * RMOE))[tid];
      u16x4 h; h[0] = f2bf(v[0]); h[1] = f2bf(v[1]); h[2] = f2bf(v[2]); h[3] = f2bf(v[3]);
      ((u16x4*)(dst + D_IN))[tid] = h;
    }
  } else {
    int r = bid - D_OUT;                    // lora_A row 0..511
    const float* src = lora_A + (size_t)r * D_IN;
    u16* dst = la + (size_t)r * D_IN;
#pragma unroll
    for (int i = 0; i < 4; ++i) {
      int c = tid + i * 256;
      f32x4 v = ((const f32x4*)src)[c];
      u16x4 h; h[0] = f2bf(v[0]); h[1] = f2bf(v[1]); h[2] = f2bf(v[2]); h[3] = f2bf(v[3]);
      ((u16x4*)dst)[c] = h;
    }
  }
}

// ---------------------------------------------------------------------------
// Kernel 3: ax GEMM  (A_cat[:, :4096] @ lora_A^T) * w * SCALING -> A_cat tail
// 128x128 tile, BK=64, 4 waves, 3-buffer LDS pipeline 2 tiles ahead with
// counted vmcnt(8); XOR-swizzled LDS (pre-swizzled global src).
// ---------------------------------------------------------------------------
__global__ __launch_bounds__(256) void k_gemm_ax(
    const u16* __restrict__ A, const u16* __restrict__ Bw,
    const float* __restrict__ wdense, u16* __restrict__ xb)
{
  __shared__ u16 sh[49152];                 // 3 x (As 8192 | Bs 8192) elems
  const int nbx = RMOE / 128;               // 4
  const int nwg = gridDim.x;                // 256 (div by 8 -> bijective)
  int bid = blockIdx.x;
  int wg = (bid & 7) * (nwg >> 3) + (bid >> 3);
  const int tm = wg / nbx, tn = wg % nbx;
  const int tid = threadIdx.x;
  const int lane = tid & 63, wave = tid >> 6;
  const int wr = wave >> 1, wc = wave & 1;
  const int l15 = lane & 15, g = lane >> 4;
  const int row0 = tm * 128, col0 = tn * 128;

  size_t offA[4], offB[4]; int dstd[4];
#pragma unroll
  for (int i = 0; i < 4; ++i) {
    int c = tid + i * 256;
    int r = c >> 3, s = (c & 7) ^ (r & 7);  // pre-swizzled source slot
    offA[i] = (size_t)(row0 + r) * KCAT + s * 8;
    offB[i] = (size_t)(col0 + r) * D_IN + s * 8;
    dstd[i] = c * 8;
  }

#define STGAX(b, kt) do { \
    _Pragma("unroll") for (int i = 0; i < 4; ++i) { \
      gload16(A  + offA[i] + (size_t)(kt) * 64, &sh[(b) * 16384 + dstd[i]]); \
      gload16(Bw + offB[i] + (size_t)(kt) * 64, &sh[(b) * 16384 + 8192 + dstd[i]]); } } while (0)

  f32x4 acc[4][4];
#pragma unroll
  for (int i = 0; i < 4; ++i)
#pragma unroll
    for (int j = 0; j < 4; ++j) acc[i][j] = (f32x4){0.f, 0.f, 0.f, 0.f};

  STGAX(0, 0);
  STGAX(1, 1);
  WAITV8();                                 // tile0 landed
  BAR();

  const int swz = (g ^ (l15 & 7)) * 8;
  for (int kt = 0; kt < D_IN / 64; ++kt) {  // 64 tiles
    if (kt + 2 < D_IN / 64) STGAX((kt + 2) % 3, kt + 2);
    const u16* As_ = &sh[(kt % 3) * 16384];
    const u16* Bs_ = &sh[(kt % 3) * 16384 + 8192];
    bf16x8 af[4][2], bfr[4][2];
#pragma unroll
    for (int i = 0; i < 4; ++i) {
      int ixa = (wr * 64 + i * 16 + l15) * 64 + swz;
      af[i][0] = *(const bf16x8*)&As_[ixa]; af[i][1] = *(const bf16x8*)&As_[ixa ^ 32];
      int ixb = (wc * 64 + i * 16 + l15) * 64 + swz;
      bfr[i][0] = *(const bf16x8*)&Bs_[ixb]; bfr[i][1] = *(const bf16x8*)&Bs_[ixb ^ 32];
    }
    __builtin_amdgcn_s_setprio(1);
#pragma unroll
    for (int i = 0; i < 4; ++i)
#pragma unroll
      for (int j = 0; j < 4; ++j)
#pragma unroll
        for (int kk = 0; kk < 2; ++kk)
          acc[i][j] = __builtin_amdgcn_mfma_f32_16x16x32_bf16(af[i][kk], bfr[j][kk], acc[i][j], 0, 0, 0);
    __builtin_amdgcn_s_setprio(0);
    if (kt >= D_IN / 64 - 2) WAITV0(); else WAITV8();
    BAR();
  }
#undef STGAX

  // epilogue: scale by gate weight, SCALING, store bf16 to A_cat tail
#pragma unroll
  for (int i = 0; i < 4; ++i) {
    int rbase = row0 + wr * 64 + i * 16 + (g << 2);
#pragma unroll
    for (int j = 0; j < 4; ++j) {
      int cb = col0 + wc * 64 + j * 16 + l15;
#pragma unroll
      for (int q = 0; q < 4; ++q) {
        int trow = rbase + q;
        float wgt = wdense[(size_t)trow * NE + (cb >> 4)];
        xb[(size_t)trow * KCAT + D_IN + cb] = f2bf(acc[i][j][q] * wgt * SCALING);
      }
    }
  }
}

// ---------------------------------------------------------------------------
// Kernel 4: main GEMM  out = A_cat @ W_cat^T  (M=8192, N=4096, K=4608)
// 256x256 tile, 8 waves (2Mx4N), BK=64, double-buffered 128 KiB LDS,
// 4 phases/K-tile, counted vmcnt(4), XOR-swizzled LDS, and one-phase-ahead
// fragment reads (each array refilled right after its last MFMA use).
// ---------------------------------------------------------------------------
#define NT (KCAT / 64)    // 72

__global__ __launch_bounds__(512, 2) void k_gemm_main(
    const u16* __restrict__ A, const u16* __restrict__ Bw, float* __restrict__ C)
{
  // [buf:2][op A|B:2][half:2][128 rows][64 cols] u16 = 128 KiB
  __shared__ u16 sh[65536];

  const int tid  = threadIdx.x;
  const int lane = tid & 63;
  const int wv   = tid >> 6;            // 0..7
  const int wm   = wv >> 2;             // 0..1
  const int wn   = wv & 3;              // 0..3
  const int l15  = lane & 15, g = lane >> 4;

  // T1: bijective XCD swizzle (512 blocks, 512 % 8 == 0)
  const int nwg = gridDim.x;
  int bid = blockIdx.x;
  int wg = (bid & 7) * (nwg >> 3) + (bid >> 3);
  const int tn = wg & 15, tm = wg >> 4; // 16 n-tiles, 32 m-tiles

  // LDS read addressing (T2 swizzle: slot ^= row&7; row&7 == l15&7)
  const int rsw   = (g ^ (l15 & 7)) * 8;
  const int aBase = l15 * 64 + rsw;
  const int bBase = ((wn & 1) * 64 + l15) * 64 + rsw;

  // staging: pre-swizzled global sources, linear gload_lds dests
  const int c0 = tid, c1 = tid + 512;
  const int r0s = c0 >> 3, s0s = (c0 & 7) ^ (r0s & 7);
  const int r1s = c1 >> 3, s1s = (c1 & 7) ^ (r1s & 7);
  const size_t offc0 = (size_t)r0s * KCAT + s0s * 8;
  const size_t offc1 = (size_t)r1s * KCAT + s1s * 8;
  const u16* pA0a = A  + (size_t)(tm * 256 +   0) * KCAT + offc0;
  const u16* pA0b = A  + (size_t)(tm * 256 +   0) * KCAT + offc1;
  const u16* pA1a = A  + (size_t)(tm * 256 + 128) * KCAT + offc0;
  const u16* pA1b = A  + (size_t)(tm * 256 + 128) * KCAT + offc1;
  const u16* pB0a = Bw + (size_t)(tn * 256 +   0) * KCAT + offc0;
  const u16* pB0b = Bw + (size_t)(tn * 256 +   0) * KCAT + offc1;
  const u16* pB1a = Bw + (size_t)(tn * 256 + 128) * KCAT + offc0;
  const u16* pB1b = Bw + (size_t)(tn * 256 + 128) * KCAT + offc1;
  const int d0 = c0 * 8, d1 = c1 * 8;

#define STG(pa, pb, base) do { \
    gload16((pa), &sh[(base) + d0]); \
    gload16((pb), &sh[(base) + d1]); \
    (pa) += 64; (pb) += 64; } while (0)

#define MM4x2(MO, NO, AF, BF) do { \
    _Pragma("unroll") for (int m_ = 0; m_ < 4; ++m_) \
    _Pragma("unroll") for (int n_ = 0; n_ < 2; ++n_) \
    _Pragma("unroll") for (int kk_ = 0; kk_ < 2; ++kk_) \
      acc[m_ + (MO)][n_ + (NO)] = __builtin_amdgcn_mfma_f32_16x16x32_bf16( \
          AF[m_][kk_], BF[n_][kk_], acc[m_ + (MO)][n_ + (NO)], 0, 0, 0); } while (0)

  f32x4 acc[8][4];
#pragma unroll
  for (int i = 0; i < 8; ++i)
#pragma unroll
    for (int j = 0; j < 4; ++j) acc[i][j] = (f32x4){0.f, 0.f, 0.f, 0.f};

  // prologue: tile0 (4 halves) + tile1 (A0,B0); then read tile0 aA,bA
  STG(pA0a, pA0b,     0);
  STG(pB0a, pB0b, 16384);
  STG(pA1a, pA1b,  8192);
  STG(pB1a, pB1b, 24576);
  STG(pA0a, pA0b, 32768 +     0);
  STG(pB0a, pB0b, 32768 + 16384);
  WAITV4();
  BAR();

  bf16x8 aA[4][2], aB[4][2], bR[2][2];
  {
    const int shA = (wm << 13);
    const int shB = 16384 + ((wn >> 1) << 13);
#pragma unroll
    for (int m = 0; m < 4; ++m) {
      int ix = shA + aBase + m * 1024;
      aA[m][0] = *(const bf16x8*)&sh[ix]; aA[m][1] = *(const bf16x8*)&sh[ix ^ 32];
    }
#pragma unroll
    for (int n = 0; n < 2; ++n) {
      int ix = shB + bBase + n * 1024;
      bR[n][0] = *(const bf16x8*)&sh[ix]; bR[n][1] = *(const bf16x8*)&sh[ix ^ 32];
    }
  }

  for (int u = 0; u < NT; ++u) {
    const int cb = (u & 1) << 15;
    const int nb = cb ^ 32768;
    const int shA  = cb + (wm << 13);
    const int shB  = cb + 16384 + ((wn >> 1) << 13);
    const int shAn = nb + (wm << 13);
    const int shBn = nb + 16384 + ((wn >> 1) << 13);

    // P1: stage A1(u+1); read aB (used P2); MFMA Q00 = aA x bA
    if (u < NT - 1) STG(pA1a, pA1b, nb + 8192);
#pragma unroll
    for (int m = 0; m < 4; ++m) {
      int ix = shA + aBase + (m + 4) * 1024;
      aB[m][0] = *(const bf16x8*)&sh[ix]; aB[m][1] = *(const bf16x8*)&sh[ix ^ 32];
    }
    BAR();
    __builtin_amdgcn_s_setprio(1);
    MM4x2(0, 0, aA, bR);
    __builtin_amdgcn_s_setprio(0);
    BAR();

    // P2: stage B1(u+1); MFMA Q10 = aB x bA; then refill bR <- bB (used P3)
    if (u < NT - 1) STG(pB1a, pB1b, nb + 24576);
    BAR();
    __builtin_amdgcn_s_setprio(1);
    MM4x2(4, 0, aB, bR);
    __builtin_amdgcn_s_setprio(0);
#pragma unroll
    for (int n = 0; n < 2; ++n) {
      int ix = shB + bBase + (n + 2) * 1024;
      bR[n][0] = *(const bf16x8*)&sh[ix]; bR[n][1] = *(const bf16x8*)&sh[ix ^ 32];
    }
    BAR();

    // P3: stage A0(u+2); MFMA Q11 = aB x bB
    if (u < NT - 2) STG(pA0a, pA0b, cb + 0);
    BAR();
    __builtin_amdgcn_s_setprio(1);
    MM4x2(4, 2, aB, bR);
    __builtin_amdgcn_s_setprio(0);
    BAR();

    // P4: stage B0(u+2); counted wait; MFMA Q01 = aA x bB;
    //     then prefetch next tile's aA', bA' (consumed next P1)
    if (u < NT - 2) { STG(pB0a, pB0b, cb + 16384); WAITV4(); }
    else            { WAITV0(); }
    BAR();
    __builtin_amdgcn_s_setprio(1);
    MM4x2(0, 2, aA, bR);
    __builtin_amdgcn_s_setprio(0);
    if (u < NT - 1) {
#pragma unroll
      for (int m = 0; m < 4; ++m) {
        int ix = shAn + aBase + m * 1024;
        aA[m][0] = *(const bf16x8*)&sh[ix]; aA[m][1] = *(const bf16x8*)&sh[ix ^ 32];
      }
#pragma unroll
      for (int n = 0; n < 2; ++n) {
        int ix = shBn + bBase + n * 1024;
        bR[n][0] = *(const bf16x8*)&sh[ix]; bR[n][1] = *(const bf16x8*)&sh[ix ^ 32];
      }
    }
    BAR();
  }
#undef STG
#undef MM4x2

  // epilogue
  const int crow0 = tm * 256 + wm * 128 + g * 4;
  const int ccol0 = tn * 256 + wn * 64 + l15;
#pragma unroll
  for (int mf = 0; mf < 8; ++mf)
#pragma unroll
    for (int n = 0; n < 4; ++n)
#pragma unroll
      for (int q = 0; q < 4; ++q)
        C[(size_t)(crow0 + mf * 16 + q) * D_OUT + ccol0 + n * 16] = acc[mf][n][q];
}

// ---------------------------------------------------------------------------
extern "C" void kernel_launch(void* const* d_in, const int* in_sizes, int n_in,
                              void* d_out, int out_size, void* d_ws, size_t ws_size,
                              hipStream_t stream) {
  const float* x      = (const float*)d_in[0];
  const float* base_w = (const float*)d_in[1];
  const float* gate_w = (const float*)d_in[2];
  const float* lora_A = (const float*)d_in[3];
  const float* lora_B = (const float*)d_in[4];
  float* out = (float*)d_out;

  char* ws = (char*)d_ws;
  u16* xb       = (u16*)ws;                                     // 75,497,472 B
  u16* wb       = (u16*)(ws + 75497472);                        // 37,748,736 B
  u16* la       = (u16*)(ws + 75497472 + 37748736);             //  4,194,304 B
  float* wdense = (float*)(ws + 75497472 + 37748736 + 4194304); //  1,048,576 B

  hipLaunchKernelGGL(k_logits,    dim3(NTOK / TT),    dim3(256), 0, stream, x, gate_w, wdense, xb);
  hipLaunchKernelGGL(k_wconv,     dim3(D_OUT + RMOE), dim3(256), 0, stream, base_w, lora_B, lora_A, wb, la);
  hipLaunchKernelGGL(k_gemm_ax,   dim3((NTOK/128) * (RMOE/128)),  dim3(256), 0, stream, xb, la, wdense, xb);
  hipLaunchKernelGGL(k_gemm_main, dim3((NTOK/256) * (D_OUT/256)), dim3(512), 0, stream, xb, wb, out);
}